// Round 10
// baseline (393.766 us; speedup 1.0000x reference)
//
#include <hip/hip_runtime.h>
#include <math.h>

#define NN 50000
#define NE 800000
#define IC 256
#define EPS 1e-5f
#define P8 50176   // padded per-copy histogram stride (= 49*1024)
#define HGRID 3128 // histogram blocks rounded to mult-of-8 (3125 active)

typedef __attribute__((ext_vector_type(8))) short short8;   // 8 bf16 (4 VGPRs)
typedef __attribute__((ext_vector_type(4))) float f32x4;    // MFMA acc

// ---------------- ws layout (float offsets) ----------------
enum : int {
  OFF_S1     = 0,                        // [256] zeroed
  OFF_S2     = 256,                      // [256] zeroed
  OFF_BAR    = 512,                      // int[16] (unused, keep layout)
  OFF_C8     = 528,                      // int[8*P8] zeroed (replicated histogram)
  ZERO_END   = OFF_C8 + 8 * P8,          // 401936
  OFF_COFF   = ZERO_END,                 // int[8*P8] per-copy bucket offsets
  OFF_START  = OFF_COFF + 8 * P8,        // int[NN+1] pad 50004
  OFF_RANK   = OFF_START + 50004,        // uchar[NE] = 200000 floats
  OFF_BSM    = OFF_RANK + 200000,        // int[1024] (unused, keep layout)
  OFF_ALS    = OFF_BSM + 1024,           // [NN*4] (16B aligned)
  OFF_ALD    = OFF_ALS + 200000,
  OFF_SRCS   = OFF_ALD + 200000,         // int[NE]
  OFF_Y32    = OFF_SRCS + 800000,        // float2[NN]
  OFF_ND4    = OFF_Y32 + 100000,         // float4[NN] = (al3s, h3x, h3y, al3d)
  OFF_BFH    = OFF_ND4 + 200000,         // ushort[131072]
  OFF_HBF    = OFF_BFH + 65536,          // ushort[NN*256]
  OFF_YLBF   = OFF_HBF + 6400000,        // ushort[NN*256]; becomes x1 in place
  WS_FLOATS  = OFF_YLBF + 6400000        // ~61.7 MB
};

__device__ __forceinline__ float lrelu(float s) { return s > 0.f ? s : 0.2f * s; }
__device__ __forceinline__ float b2f(unsigned short u) {
  return __uint_as_float(((unsigned)u) << 16);
}
__device__ __forceinline__ unsigned short f2bf(float f) {  // RNE
  unsigned u = __float_as_uint(f);
  return (unsigned short)((u + 0x7fffu + ((u >> 16) & 1u)) >> 16);
}
// hardware packed RNE f32x2 -> bf16x2 (lo -> low half). Same rounding as f2bf.
__device__ __forceinline__ unsigned cvtpk(float lo, float hi) {
  unsigned r;
  asm("v_cvt_pk_bf16_f32 %0, %1, %2" : "=v"(r) : "v"(lo), "v"(hi));
  return r;
}

// ---------------- prologue: BN1 stats (8x ILP) | weight prep ----------------
__global__ __launch_bounds__(256) void k_prep(const float* __restrict__ x,
                                              float* __restrict__ S1,
                                              float* __restrict__ S2,
                                              const float* __restrict__ Wlin,
                                              const float* __restrict__ Wcon,
                                              unsigned short* __restrict__ Bfh) {
  int b = blockIdx.x;
  if (b < 1024) {
    int c = threadIdx.x;
    float s1 = 0.f, s2 = 0.f;
    for (int r0 = b * 8; r0 < NN; r0 += 8192) {
#pragma unroll
      for (int u = 0; u < 8; ++u) {
        int r = r0 + u;
        if (r < NN) {
          float v = x[r * IC + c];
          s1 += v;
          s2 = fmaf(v, v, s2);
        }
      }
    }
    atomicAdd(&S1[c], s1);
    atomicAdd(&S2[c], s2);
  } else {
    int id = (b - 1024) * 256 + threadIdx.x;  // < 131072
    int j = id & 7, lane = (id >> 3) & 63, nt = (id >> 9) & 31, ks = id >> 14;
    int k = ks * 32 + ((lane >> 4) << 3) + j;
    int n = nt * 16 + (lane & 15);
    float v = (n < 256) ? Wlin[k * 256 + n] : Wcon[k * 256 + (n - 256)];
    Bfh[id] = f2bf(v);
  }
}

// ---------------- BN stats (layer 2): vectorized ushort4 + LDS wave reduce -------
__global__ __launch_bounds__(256) void k_bnstats2(const ushort4* __restrict__ x1q,
                                                  float* __restrict__ S1,
                                                  float* __restrict__ S2) {
  __shared__ float red1[4][256], red2[4][256];
  const int tid = threadIdx.x, wave = tid >> 6, lane = tid & 63;
  float s1a = 0.f, s1b = 0.f, s1c = 0.f, s1d = 0.f;
  float s2a = 0.f, s2b = 0.f, s2c = 0.f, s2d = 0.f;
  for (int r = blockIdx.x * 4 + wave; r < NN; r += gridDim.x * 4) {
    ushort4 v = x1q[r * 64 + lane];
    float f0 = b2f(v.x), f1 = b2f(v.y), f2 = b2f(v.z), f3 = b2f(v.w);
    s1a += f0; s2a = fmaf(f0, f0, s2a);
    s1b += f1; s2b = fmaf(f1, f1, s2b);
    s1c += f2; s2c = fmaf(f2, f2, s2c);
    s1d += f3; s2d = fmaf(f3, f3, s2d);
  }
  red1[wave][lane * 4 + 0] = s1a; red2[wave][lane * 4 + 0] = s2a;
  red1[wave][lane * 4 + 1] = s1b; red2[wave][lane * 4 + 1] = s2b;
  red1[wave][lane * 4 + 2] = s1c; red2[wave][lane * 4 + 2] = s2c;
  red1[wave][lane * 4 + 3] = s1d; red2[wave][lane * 4 + 3] = s2d;
  __syncthreads();
  float a = red1[0][tid] + red1[1][tid] + red1[2][tid] + red1[3][tid];
  float b = red2[0][tid] + red2[1][tid] + red2[2][tid] + red2[3][tid];
  atomicAdd(&S1[tid], a);
  atomicAdd(&S2[tid], b);
}

// ---------------- MFMA dual GEMM + leading histogram ----------------
// blocks [0,3125): 8-way replicated dst histogram + rank capture — placed FIRST
// so the latency-bound atomic blocks interleave with the MFMA blocks instead of
// forming a low-utilization tail (r9 suspicion: ~10-15us tail).
// blocks [3125,3128): idle pad (keeps GEMM offset % 8 == 0 for XCD pairing).
// blocks [3128,3128+1568): GEMM, XCD-paired decode, single-buffer Ah, two
// barriers per k-step, launch_bounds(256,4) EXACTLY (r8: (256,8) spilled acc).
__global__ __launch_bounds__(256, 4) void k_gemm(const float* __restrict__ x,
                                                 const float* __restrict__ S1,
                                                 const float* __restrict__ S2,
                                                 const float* __restrict__ bng,
                                                 const float* __restrict__ bnb,
                                                 const unsigned short* __restrict__ Bfh,
                                                 unsigned short* __restrict__ ylbf,
                                                 unsigned short* __restrict__ hbf,
                                                 const float* __restrict__ asrc,
                                                 const float* __restrict__ adst,
                                                 float* __restrict__ als,
                                                 float* __restrict__ ald,
                                                 const int* __restrict__ dst,
                                                 int* __restrict__ counts8,
                                                 unsigned char* __restrict__ rank8) {
  const int tid = threadIdx.x;
  const int b = blockIdx.x;
  if (b < HGRID) {  // ---- histogram first ----
    if (b >= 3125) return;
    int e = b * 256 + tid;                  // exactly NE
    int copy = b & 7;                       // scatter reconstructs via blockIdx&7
    int old = atomicAdd(&counts8[copy * P8 + dst[e]], 1);
    rank8[e] = (unsigned char)old;          // max degree ~40 << 255
    return;
  }
  const int g = b - HGRID;                    // HGRID % 8 == 0 keeps XCD phase
  const int row_blk = (g >> 4) * 8 + (g & 7); // pair partner is g^8 (same XCD)
  const int bn = (g >> 3) & 1;
  if (row_blk >= 782) return;
  const int row0 = row_blk * 64;
  __shared__ unsigned short Ah[2048];
  __shared__ float sc[256], sh[256];
  const int wave = tid >> 6, lane = tid & 63;
  {
    float mu = S1[tid] * (1.f / NN);
    float var = S2[tid] * (1.f / NN) - mu * mu;
    float ss = bng[tid] / sqrtf(var + EPS);
    sc[tid] = ss;
    sh[tid] = bnb[tid] - mu * ss;
  }
  const float4* x4 = (const float4*)x;
  const short8* Bh8 = (const short8*)Bfh;
  f32x4 acc[4][4];
#pragma unroll
  for (int i = 0; i < 4; ++i)
#pragma unroll
    for (int j = 0; j < 4; ++j) acc[i][j] = (f32x4){0.f, 0.f, 0.f, 0.f};

  const int m = tid >> 2, kg = tid & 3;
  const int r = row0 + m;
  const int aaddr = (((m >> 4) * 64) + ((m & 15) | (kg << 4))) * 8;
  __syncthreads();

  for (int ks = 0; ks < 8; ++ks) {
    const int c0 = ks * 32 + kg * 8;
    float v[8];
    if (r < NN) {
      int base = (r * IC + c0) >> 2;
      float4 fa = x4[base], fb = x4[base + 1];
      v[0] = fa.x; v[1] = fa.y; v[2] = fa.z; v[3] = fa.w;
      v[4] = fb.x; v[5] = fb.y; v[6] = fb.z; v[7] = fb.w;
#pragma unroll
      for (int j = 0; j < 8; ++j) v[j] = fmaf(v[j], sc[c0 + j], sh[c0 + j]);
    } else {
#pragma unroll
      for (int j = 0; j < 8; ++j) v[j] = 0.f;
    }
    unsigned ph[4];
#pragma unroll
    for (int j = 0; j < 4; ++j) ph[j] = cvtpk(v[2 * j], v[2 * j + 1]);
    *(uint4*)&Ah[aaddr] = make_uint4(ph[0], ph[1], ph[2], ph[3]);
    __syncthreads();

    short8 ah[4];
#pragma unroll
    for (int mt = 0; mt < 4; ++mt)
      ah[mt] = *(const short8*)&Ah[(mt * 64 + lane) * 8];
#pragma unroll
    for (int nt = 0; nt < 4; ++nt) {
      short8 bh = Bh8[(ks * 32 + bn * 16 + wave * 4 + nt) * 64 + lane];
#pragma unroll
      for (int mt = 0; mt < 4; ++mt)
        acc[mt][nt] = __builtin_amdgcn_mfma_f32_16x16x32_bf16(ah[mt], bh, acc[mt][nt], 0, 0, 0);
    }
    __syncthreads();
  }
  // epilogue: C/D layout col=lane&15, row=(lane>>4)*4+reg
  const int colq = lane & 15, quad = lane >> 4;
  if (bn == 0) {
#pragma unroll
    for (int mt = 0; mt < 4; ++mt)
#pragma unroll
      for (int reg = 0; reg < 4; ++reg) {
        int rr = row0 + mt * 16 + quad * 4 + reg;
        if (rr < NN) {
#pragma unroll
          for (int nt = 0; nt < 4; ++nt)
            ylbf[rr * IC + wave * 64 + nt * 16 + colq] = f2bf(acc[mt][nt][reg]);
        }
      }
  } else {
    const int head = wave;
    float asv[4], adv[4];
#pragma unroll
    for (int j = 0; j < 4; ++j) {
      asv[j] = asrc[head * 64 + j * 16 + colq];
      adv[j] = adst[head * 64 + j * 16 + colq];
    }
#pragma unroll
    for (int mt = 0; mt < 4; ++mt)
#pragma unroll
      for (int reg = 0; reg < 4; ++reg) {
        int rr = row0 + mt * 16 + quad * 4 + reg;
        float sA = 0.f, dA = 0.f;
#pragma unroll
        for (int j = 0; j < 4; ++j) {
          float hA = acc[mt][j][reg];
          sA = fmaf(hA, asv[j], sA);
          dA = fmaf(hA, adv[j], dA);
          if (rr < NN) hbf[rr * IC + head * 64 + j * 16 + colq] = f2bf(hA);
        }
#pragma unroll
        for (int off = 1; off < 16; off <<= 1) {
          sA += __shfl_xor(sA, off, 64);
          dA += __shfl_xor(dA, off, 64);
        }
        if (rr < NN) {
          if (colq == 0) als[rr * 4 + head] = sA;
          else if (colq == 1) ald[rr * 4 + head] = dA;
        }
      }
  }
}

// ---------------- CSR scan over 8 replicated histograms (1024 thr) ---------------
// block 0 also re-zeroes S1/S2 for layer 2 (k_gemm consumed layer-1 stats).
__global__ __launch_bounds__(1024) void k_scan(const int* __restrict__ counts8,
                                               int* __restrict__ coff,
                                               int* __restrict__ start,
                                               float* __restrict__ S1,
                                               float* __restrict__ S2) {
  __shared__ int red[16];
  __shared__ int buf[1024];
  const int tid = threadIdx.x, b = blockIdx.x;
  const int base = b * 1024;
  int pre = 0;
  for (int i = tid; i < base; i += 1024) {
    int s = 0;
#pragma unroll
    for (int k = 0; k < 8; ++k) s += counts8[k * P8 + i];
    pre += s;
  }
#pragma unroll
  for (int off = 1; off < 64; off <<= 1) pre += __shfl_xor(pre, off, 64);
  if ((tid & 63) == 0) red[tid >> 6] = pre;
  if (b == 0 && tid < 256) {
    S1[tid] = 0.f;
    S2[tid] = 0.f;
  }
  __syncthreads();
  int bpre = 0;
#pragma unroll
  for (int w = 0; w < 16; ++w) bpre += red[w];
  const int i = base + tid;  // < P8 always (49*1024 == P8)
  int pc[8];
  int tot = 0;
#pragma unroll
  for (int k = 0; k < 8; ++k) {
    pc[k] = counts8[k * P8 + i];
    tot += pc[k];
  }
  buf[tid] = tot;
  __syncthreads();
  for (int off = 1; off < 1024; off <<= 1) {
    int t = (tid >= off) ? buf[tid - off] : 0;
    __syncthreads();
    buf[tid] += t;
    __syncthreads();
  }
  int ex = bpre + buf[tid] - tot;  // exclusive global prefix for element i
  int run = ex;
#pragma unroll
  for (int k = 0; k < 8; ++k) {
    coff[k * P8 + i] = run;
    run += pc[k];
  }
  if (i < NN) start[i] = ex;
  if (b == 48 && tid == 1023) start[NN] = ex + tot;
}

// ---------------- atomic-free scatter: pos = coff[copy][dst] + rank ------------
__global__ __launch_bounds__(256) void k_scatter(const int* __restrict__ src,
                                                 const int* __restrict__ dst,
                                                 const int* __restrict__ coff,
                                                 const unsigned char* __restrict__ rank8,
                                                 int* __restrict__ srcs) {
  int e = blockIdx.x * 256 + threadIdx.x;
  int copy = blockIdx.x & 7;  // matches histogram block mapping
  int pos = coff[copy * P8 + dst[e]] + (int)rank8[e];
  srcs[pos] = src[e];
}

// ---------------- layer-1 aggregation: wave/node; no-max softmax; p in LDS -------
// r9 closed concurrency levers (unroll-8 = unroll-4 = 76us; fabric-bound at
// ~3.7 TB/s L2-miss traffic). This round: SRC-HALF SPLIT gather — sweep edges
// with src<25000 then src>=25000, halving the instantaneous working set
// (25.6 -> 12.8 MB) to raise per-XCD L2 hit rate. Branch is wave-uniform
// (sv broadcast via shfl). Pre-commit: FETCH unchanged => pattern ceiling.
__global__ __launch_bounds__(256) void k_agg(const ushort4* __restrict__ hq,
                                             ushort4* __restrict__ x1,
                                             const float4* __restrict__ als4,
                                             const float4* __restrict__ ald4,
                                             const int* __restrict__ start,
                                             const int* __restrict__ srcs,
                                             const float4* __restrict__ lb4,
                                             const float4* __restrict__ cb4) {
  __shared__ float lsp[1024];          // per-edge p: [wave][edge j][head]
  const int tid = threadIdx.x;
  const int wave = tid >> 6, lane = tid & 63, head = lane >> 4;
  const int n = blockIdx.x * 4 + wave;
  const float* als = (const float*)als4;
  const int s = start[n], t = start[n + 1];
  const int deg = t - s;
  const float4 aldv = ald4[n];
  int svk = -1;
  float p0 = 0.f, p1 = 0.f, p2 = 0.f, p3 = 0.f;
  if (lane < deg) {
    svk = srcs[s + lane];
    float4 a = als4[svk];
    p0 = __expf(lrelu(a.x + aldv.x));
    p1 = __expf(lrelu(a.y + aldv.y));
    p2 = __expf(lrelu(a.z + aldv.z));
    p3 = __expf(lrelu(a.w + aldv.w));
  }
  *(float4*)&lsp[wave * 256 + lane * 4] = make_float4(p0, p1, p2, p3);
  float d0 = p0, d1 = p1, d2 = p2, d3 = p3;
  const float aldh = head == 0 ? aldv.x : head == 1 ? aldv.y : head == 2 ? aldv.z : aldv.w;
  if (deg > 64) {
    for (int i = s + 64 + lane; i < t; i += 64) {
      float4 a = als4[srcs[i]];
      d0 += __expf(lrelu(a.x + aldv.x));
      d1 += __expf(lrelu(a.y + aldv.y));
      d2 += __expf(lrelu(a.z + aldv.z));
      d3 += __expf(lrelu(a.w + aldv.w));
    }
  }
#pragma unroll
  for (int off = 1; off < 64; off <<= 1) {
    d0 += __shfl_xor(d0, off, 64);
    d1 += __shfl_xor(d1, off, 64);
    d2 += __shfl_xor(d2, off, 64);
    d3 += __shfl_xor(d3, off, 64);
  }
  const float inv =
      1.f / ((head == 0 ? d0 : head == 1 ? d1 : head == 2 ? d2 : d3) + 1e-16f);
  float a0 = 0.f, a1 = 0.f, a2 = 0.f, a3 = 0.f;
  const int cnt = min(deg, 64);
  const int wbase = wave * 256 + head;
#pragma unroll
  for (int half = 0; half < 2; ++half) {
    const int lo = half * 25000;
    const int hi = lo + 25000;
    int j = 0;
    for (; j + 4 <= cnt; j += 4) {
      int sv0 = __shfl(svk, j, 64), sv1 = __shfl(svk, j + 1, 64);
      int sv2 = __shfl(svk, j + 2, 64), sv3 = __shfl(svk, j + 3, 64);
      if (sv0 >= lo && sv0 < hi) {
        float w = lsp[wbase + j * 4];
        ushort4 hv = hq[sv0 * 64 + lane];
        a0 = fmaf(w, b2f(hv.x), a0); a1 = fmaf(w, b2f(hv.y), a1);
        a2 = fmaf(w, b2f(hv.z), a2); a3 = fmaf(w, b2f(hv.w), a3);
      }
      if (sv1 >= lo && sv1 < hi) {
        float w = lsp[wbase + j * 4 + 4];
        ushort4 hv = hq[sv1 * 64 + lane];
        a0 = fmaf(w, b2f(hv.x), a0); a1 = fmaf(w, b2f(hv.y), a1);
        a2 = fmaf(w, b2f(hv.z), a2); a3 = fmaf(w, b2f(hv.w), a3);
      }
      if (sv2 >= lo && sv2 < hi) {
        float w = lsp[wbase + j * 4 + 8];
        ushort4 hv = hq[sv2 * 64 + lane];
        a0 = fmaf(w, b2f(hv.x), a0); a1 = fmaf(w, b2f(hv.y), a1);
        a2 = fmaf(w, b2f(hv.z), a2); a3 = fmaf(w, b2f(hv.w), a3);
      }
      if (sv3 >= lo && sv3 < hi) {
        float w = lsp[wbase + j * 4 + 12];
        ushort4 hv = hq[sv3 * 64 + lane];
        a0 = fmaf(w, b2f(hv.x), a0); a1 = fmaf(w, b2f(hv.y), a1);
        a2 = fmaf(w, b2f(hv.z), a2); a3 = fmaf(w, b2f(hv.w), a3);
      }
    }
    for (; j < cnt; ++j) {
      int sv = __shfl(svk, j, 64);
      if (sv >= lo && sv < hi) {
        float w = lsp[wbase + j * 4];
        ushort4 hv = hq[sv * 64 + lane];
        a0 = fmaf(w, b2f(hv.x), a0);
        a1 = fmaf(w, b2f(hv.y), a1);
        a2 = fmaf(w, b2f(hv.z), a2);
        a3 = fmaf(w, b2f(hv.w), a3);
      }
    }
    if (deg > 64) {
      for (int i = s + 64; i < t; ++i) {
        int sv = srcs[i];
        if (sv >= lo && sv < hi) {
          float av = als[sv * 4 + head];
          float p = __expf(lrelu(av + aldh));
          ushort4 hv = hq[sv * 64 + lane];
          a0 = fmaf(p, b2f(hv.x), a0);
          a1 = fmaf(p, b2f(hv.y), a1);
          a2 = fmaf(p, b2f(hv.z), a2);
          a3 = fmaf(p, b2f(hv.w), a3);
        }
      }
    }
  }
  ushort4 yb = x1[n * 64 + lane];
  float4 bb1 = lb4[lane], bb2 = cb4[lane];
  ushort4 rb;
  rb.x = f2bf(fmaxf(fmaf(a0, inv, b2f(yb.x) + bb1.x + bb2.x), 0.f));
  rb.y = f2bf(fmaxf(fmaf(a1, inv, b2f(yb.y) + bb1.y + bb2.y), 0.f));
  rb.z = f2bf(fmaxf(fmaf(a2, inv, b2f(yb.z) + bb1.z + bb2.z), 0.f));
  rb.w = f2bf(fmaxf(fmaf(a3, inv, b2f(yb.w) + bb1.w + bb2.w), 0.f));
  x1[n * 64 + lane] = rb;
}

// ---------------- layer 2 node kernel: inline BN-finalize + projections ----------
__global__ __launch_bounds__(256) void k_node2(const ushort4* __restrict__ x1,
                                               const float* __restrict__ S1,
                                               const float* __restrict__ S2,
                                               const float* __restrict__ g3,
                                               const float* __restrict__ b3,
                                               const float4* __restrict__ Wl4,
                                               const float4* __restrict__ Wc4,
                                               const float* __restrict__ a3s,
                                               const float* __restrict__ a3d,
                                               const float* __restrict__ l3b,
                                               const float* __restrict__ c3b,
                                               float2* __restrict__ y32,
                                               float4* __restrict__ nd4) {
  __shared__ float sc[256], sh[256];
  const int tid = threadIdx.x;
  {
    float mu = S1[tid] * (1.f / NN);
    float var = S2[tid] * (1.f / NN) - mu * mu;
    float ss = g3[tid] / sqrtf(var + EPS);
    sc[tid] = ss;
    sh[tid] = b3[tid] - mu * ss;
  }
  __syncthreads();
  const int n = blockIdx.x * 4 + (tid >> 6);
  const int lane = tid & 63;
  ushort4 xb = x1[n * 64 + lane];
  float x0 = fmaf(b2f(xb.x), sc[lane * 4 + 0], sh[lane * 4 + 0]);
  float x1v = fmaf(b2f(xb.y), sc[lane * 4 + 1], sh[lane * 4 + 1]);
  float x2 = fmaf(b2f(xb.z), sc[lane * 4 + 2], sh[lane * 4 + 2]);
  float x3 = fmaf(b2f(xb.w), sc[lane * 4 + 3], sh[lane * 4 + 3]);
  float4 wa = Wl4[lane * 2], wb = Wl4[lane * 2 + 1];
  float y0 = x0 * wa.x + x1v * wa.z + x2 * wb.x + x3 * wb.z;
  float y1 = x0 * wa.y + x1v * wa.w + x2 * wb.y + x3 * wb.w;
  float4 ca = Wc4[lane * 2], cb = Wc4[lane * 2 + 1];
  float g0 = x0 * ca.x + x1v * ca.z + x2 * cb.x + x3 * cb.z;
  float g1 = x0 * ca.y + x1v * ca.w + x2 * cb.y + x3 * cb.w;
#pragma unroll
  for (int off = 1; off < 64; off <<= 1) {
    y0 += __shfl_xor(y0, off, 64);
    y1 += __shfl_xor(y1, off, 64);
    g0 += __shfl_xor(g0, off, 64);
    g1 += __shfl_xor(g1, off, 64);
  }
  if (lane == 0) {
    y32[n] = make_float2(y0 + l3b[0] + c3b[0], y1 + l3b[1] + c3b[1]);
    nd4[n] = make_float4(g0 * a3s[0] + g1 * a3s[1], g0, g1,
                         g0 * a3d[0] + g1 * a3d[1]);
  }
}

// ---------------- layer 2 softmax-aggregate + output, single pass ----------------
__global__ __launch_bounds__(256) void k_final(const int* __restrict__ start,
                                               const int* __restrict__ srcs,
                                               const float4* __restrict__ nd4,
                                               const float2* __restrict__ y32,
                                               float* __restrict__ out) {
  const int tid = threadIdx.x;
  const int n = blockIdx.x * 16 + (tid >> 4);
  const int li = tid & 15;
  const int s = start[n], t = start[n + 1];
  const float ad = nd4[n].w;
  float den = 0.f, a0 = 0.f, a1 = 0.f;
  for (int ii = s + li; ii < t; ii += 16) {
    float4 vv = nd4[srcs[ii]];
    float p = __expf(lrelu(vv.x + ad));
    den += p;
    a0 = fmaf(p, vv.y, a0);
    a1 = fmaf(p, vv.z, a1);
  }
#pragma unroll
  for (int off = 1; off < 16; off <<= 1) {
    den += __shfl_xor(den, off, 64);
    a0 += __shfl_xor(a0, off, 64);
    a1 += __shfl_xor(a1, off, 64);
  }
  if (li == 0) {
    float2 y = y32[n];
    float inv = 1.f / (den + 1e-16f);
    out[2 * n] = fmaxf(fmaf(a0, inv, y.x), 0.f);
    out[2 * n + 1] = fmaxf(fmaf(a1, inv, y.y), 0.f);
  }
}

extern "C" void kernel_launch(void* const* d_in, const int* in_sizes, int n_in,
                              void* d_out, int out_size, void* d_ws, size_t ws_size,
                              hipStream_t stream) {
  const float* x = (const float*)d_in[0];
  const int* ei = (const int*)d_in[1];
  const float* bn1_g = (const float*)d_in[2];
  const float* bn1_b = (const float*)d_in[3];
  const float* lin1_W = (const float*)d_in[4];
  const float* lin1_b = (const float*)d_in[5];
  const float* con1_W = (const float*)d_in[6];
  const float* con1_as = (const float*)d_in[7];
  const float* con1_ad = (const float*)d_in[8];
  const float* con1_b = (const float*)d_in[9];
  const float* bn3_g = (const float*)d_in[10];
  const float* bn3_b = (const float*)d_in[11];
  const float* lin3_W = (const float*)d_in[12];
  const float* lin3_b = (const float*)d_in[13];
  const float* con3_W = (const float*)d_in[14];
  const float* con3_as = (const float*)d_in[15];
  const float* con3_ad = (const float*)d_in[16];
  const float* con3_b = (const float*)d_in[17];
  float* ws = (float*)d_ws;
  const int* srcA = ei;
  const int* dstA = ei + NE;

  float* S1 = ws + OFF_S1;
  float* S2 = ws + OFF_S2;
  int* counts8 = (int*)(ws + OFF_C8);
  int* coff = (int*)(ws + OFF_COFF);
  int* start = (int*)(ws + OFF_START);
  unsigned char* rank8 = (unsigned char*)(ws + OFF_RANK);
  float* als = ws + OFF_ALS;
  float* ald = ws + OFF_ALD;
  int* srcs = (int*)(ws + OFF_SRCS);
  float2* y32 = (float2*)(ws + OFF_Y32);
  float4* nd4 = (float4*)(ws + OFF_ND4);
  unsigned short* Bfh = (unsigned short*)(ws + OFF_BFH);
  unsigned short* hbf = (unsigned short*)(ws + OFF_HBF);
  unsigned short* ylbf = (unsigned short*)(ws + OFF_YLBF);  // becomes x1 in place

  hipMemsetAsync(ws, 0, (size_t)ZERO_END * sizeof(float), stream);

  k_prep<<<1536, 256, 0, stream>>>(x, S1, S2, lin1_W, con1_W, Bfh);
  k_gemm<<<HGRID + 1568, 256, 0, stream>>>(x, S1, S2, bn1_g, bn1_b, Bfh, ylbf,
                                           hbf, con1_as, con1_ad, als, ald,
                                           dstA, counts8, rank8);
  k_scan<<<49, 1024, 0, stream>>>(counts8, coff, start, S1, S2);
  k_scatter<<<3125, 256, 0, stream>>>(srcA, dstA, coff, rank8, srcs);
  k_agg<<<12500, 256, 0, stream>>>((const ushort4*)hbf, (ushort4*)ylbf,
                                   (const float4*)als, (const float4*)ald, start,
                                   srcs, (const float4*)lin1_b,
                                   (const float4*)con1_b);
  k_bnstats2<<<512, 256, 0, stream>>>((const ushort4*)ylbf, S1, S2);
  k_node2<<<12500, 256, 0, stream>>>((const ushort4*)ylbf, S1, S2, bn3_g, bn3_b,
                                     (const float4*)lin3_W, (const float4*)con3_W,
                                     con3_as, con3_ad, lin3_b, con3_b, y32, nd4);
  k_final<<<3125, 256, 0, stream>>>(start, srcs, nd4, y32, (float*)d_out);
}

// Round 11
// 371.036 us; speedup vs baseline: 1.0613x; 1.0613x over previous
//
#include <hip/hip_runtime.h>
#include <math.h>

#define NN 50000
#define NE 800000
#define IC 256
#define EPS 1e-5f
#define P8 50176   // padded per-copy histogram stride (= 49*1024)

typedef __attribute__((ext_vector_type(8))) short short8;   // 8 bf16 (4 VGPRs)
typedef __attribute__((ext_vector_type(4))) float f32x4;    // MFMA acc

// ---------------- ws layout (float offsets) ----------------
enum : int {
  OFF_S1     = 0,                        // [256] zeroed (BN1 stats)
  OFF_S2     = 256,                      // [256] zeroed
  OFF_BAR    = 512,                      // int[16] (unused, keep layout)
  OFF_S32    = 528,                      // float[8*512] zeroed (layer2 stats, 8-way)
  OFF_C8     = OFF_S32 + 4096,           // int[8*P8] zeroed (replicated histogram)
  ZERO_END   = OFF_C8 + 8 * P8,
  OFF_COFF   = ZERO_END,                 // int[8*P8] per-copy bucket offsets
  OFF_START  = OFF_COFF + 8 * P8,        // int[NN+1] pad 50004
  OFF_RANK   = OFF_START + 50004,        // uchar[NE] = 200000 floats
  OFF_BSM    = OFF_RANK + 200000,        // int[1024] (unused, keep layout)
  OFF_ALS    = OFF_BSM + 1024,           // [NN*4] (16B aligned)
  OFF_ALD    = OFF_ALS + 200000,
  OFF_SRCS   = OFF_ALD + 200000,         // int[NE]
  OFF_Y32    = OFF_SRCS + 800000,        // float2[NN]
  OFF_ND4    = OFF_Y32 + 100000,         // float4[NN] = (al3s, h3x, h3y, al3d)
  OFF_BFH    = OFF_ND4 + 200000,         // ushort[131072]
  OFF_HBF    = OFF_BFH + 65536,          // ushort[NN*256]
  OFF_YLBF   = OFF_HBF + 6400000,        // ushort[NN*256]; becomes x1 in place
  WS_FLOATS  = OFF_YLBF + 6400000        // ~61.7 MB
};

__device__ __forceinline__ float lrelu(float s) { return s > 0.f ? s : 0.2f * s; }
__device__ __forceinline__ float b2f(unsigned short u) {
  return __uint_as_float(((unsigned)u) << 16);
}
__device__ __forceinline__ unsigned short f2bf(float f) {  // RNE
  unsigned u = __float_as_uint(f);
  return (unsigned short)((u + 0x7fffu + ((u >> 16) & 1u)) >> 16);
}
// hardware packed RNE f32x2 -> bf16x2 (lo -> low half). Same rounding as f2bf.
__device__ __forceinline__ unsigned cvtpk(float lo, float hi) {
  unsigned r;
  asm("v_cvt_pk_bf16_f32 %0, %1, %2" : "=v"(r) : "v"(lo), "v"(hi));
  return r;
}

// ---------------- prologue: BN1 stats (8x ILP) | weight prep ----------------
__global__ __launch_bounds__(256) void k_prep(const float* __restrict__ x,
                                              float* __restrict__ S1,
                                              float* __restrict__ S2,
                                              const float* __restrict__ Wlin,
                                              const float* __restrict__ Wcon,
                                              unsigned short* __restrict__ Bfh) {
  int b = blockIdx.x;
  if (b < 1024) {
    int c = threadIdx.x;
    float s1 = 0.f, s2 = 0.f;
    for (int r0 = b * 8; r0 < NN; r0 += 8192) {
#pragma unroll
      for (int u = 0; u < 8; ++u) {
        int r = r0 + u;
        if (r < NN) {
          float v = x[r * IC + c];
          s1 += v;
          s2 = fmaf(v, v, s2);
        }
      }
    }
    atomicAdd(&S1[c], s1);
    atomicAdd(&S2[c], s2);
  } else {
    int id = (b - 1024) * 256 + threadIdx.x;  // < 131072
    int j = id & 7, lane = (id >> 3) & 63, nt = (id >> 9) & 31, ks = id >> 14;
    int k = ks * 32 + ((lane >> 4) << 3) + j;
    int n = nt * 16 + (lane & 15);
    float v = (n < 256) ? Wlin[k * 256 + n] : Wcon[k * 256 + (n - 256)];
    Bfh[id] = f2bf(v);
  }
}

// ---------------- MFMA dual GEMM (r7-proven core) + shadowed histogram ----------
// blocks [0,1568): GEMM, XCD-paired decode, single-buffer Ah, two barriers per
// k-step, launch_bounds(256,4) EXACTLY (r8: (256,8) spilled acc; r5/r6 dbuf
// pipeline caused write amplification — both keep-reverted).
// NEW: coalesced epilogue — C-tile staged through 16KB LDS, written as 16B/lane
// uint4 rows (r7 WRITE was 84MB vs 51.2 ideal = 1.64x partial-line amplification
// from scattered 2B stores).
// blocks [1568,1568+3125): 8-way replicated dst histogram + rank capture.
__global__ __launch_bounds__(256, 4) void k_gemm(const float* __restrict__ x,
                                                 const float* __restrict__ S1,
                                                 const float* __restrict__ S2,
                                                 const float* __restrict__ bng,
                                                 const float* __restrict__ bnb,
                                                 const unsigned short* __restrict__ Bfh,
                                                 unsigned short* __restrict__ ylbf,
                                                 unsigned short* __restrict__ hbf,
                                                 const float* __restrict__ asrc,
                                                 const float* __restrict__ adst,
                                                 float* __restrict__ als,
                                                 float* __restrict__ ald,
                                                 const int* __restrict__ dst,
                                                 int* __restrict__ counts8,
                                                 unsigned char* __restrict__ rank8) {
  const int tid = threadIdx.x;
  const int g = blockIdx.x;
  if (g >= 1568) {  // ---- histogram (1568 % 8 == 0 keeps copy = (e>>8)&7) ----
    int hb = g - 1568;
    int e = hb * 256 + tid;                 // exactly NE
    int copy = hb & 7;
    int old = atomicAdd(&counts8[copy * P8 + dst[e]], 1);
    rank8[e] = (unsigned char)old;          // max degree ~40 << 255
    return;
  }
  const int row_blk = (g >> 4) * 8 + (g & 7); // pair partner is g^8 (same XCD)
  const int bn = (g >> 3) & 1;
  if (row_blk >= 782) return;
  const int row0 = row_blk * 64;
  __shared__ unsigned short Ah[2048];
  __shared__ float sc[256], sh[256];
  __shared__ unsigned short Cst[32 * 256];   // 16KB epilogue staging
  const int wave = tid >> 6, lane = tid & 63;
  {
    float mu = S1[tid] * (1.f / NN);
    float var = S2[tid] * (1.f / NN) - mu * mu;
    float ss = bng[tid] / sqrtf(var + EPS);
    sc[tid] = ss;
    sh[tid] = bnb[tid] - mu * ss;
  }
  const float4* x4 = (const float4*)x;
  const short8* Bh8 = (const short8*)Bfh;
  f32x4 acc[4][4];
#pragma unroll
  for (int i = 0; i < 4; ++i)
#pragma unroll
    for (int j = 0; j < 4; ++j) acc[i][j] = (f32x4){0.f, 0.f, 0.f, 0.f};

  const int m = tid >> 2, kg = tid & 3;
  const int r = row0 + m;
  const int aaddr = (((m >> 4) * 64) + ((m & 15) | (kg << 4))) * 8;
  __syncthreads();

  for (int ks = 0; ks < 8; ++ks) {
    const int c0 = ks * 32 + kg * 8;
    float v[8];
    if (r < NN) {
      int base = (r * IC + c0) >> 2;
      float4 fa = x4[base], fb = x4[base + 1];
      v[0] = fa.x; v[1] = fa.y; v[2] = fa.z; v[3] = fa.w;
      v[4] = fb.x; v[5] = fb.y; v[6] = fb.z; v[7] = fb.w;
#pragma unroll
      for (int j = 0; j < 8; ++j) v[j] = fmaf(v[j], sc[c0 + j], sh[c0 + j]);
    } else {
#pragma unroll
      for (int j = 0; j < 8; ++j) v[j] = 0.f;
    }
    unsigned ph[4];
#pragma unroll
    for (int j = 0; j < 4; ++j) ph[j] = cvtpk(v[2 * j], v[2 * j + 1]);
    *(uint4*)&Ah[aaddr] = make_uint4(ph[0], ph[1], ph[2], ph[3]);
    __syncthreads();

    short8 ah[4];
#pragma unroll
    for (int mt = 0; mt < 4; ++mt)
      ah[mt] = *(const short8*)&Ah[(mt * 64 + lane) * 8];
#pragma unroll
    for (int nt = 0; nt < 4; ++nt) {
      short8 bh = Bh8[(ks * 32 + bn * 16 + wave * 4 + nt) * 64 + lane];
#pragma unroll
      for (int mt = 0; mt < 4; ++mt)
        acc[mt][nt] = __builtin_amdgcn_mfma_f32_16x16x32_bf16(ah[mt], bh, acc[mt][nt], 0, 0, 0);
    }
    __syncthreads();
  }
  // epilogue: C/D layout col=lane&15, row=(lane>>4)*4+reg. Stage 32 rows at a
  // time in Cst, then write fully-coalesced 16B chunks.
  const int colq = lane & 15, quad = lane >> 4;
  if (bn == 0) {
#pragma unroll
    for (int half = 0; half < 2; ++half) {
#pragma unroll
      for (int mh = 0; mh < 2; ++mh) {
        const int mt = half * 2 + mh;
#pragma unroll
        for (int reg = 0; reg < 4; ++reg)
#pragma unroll
          for (int nt = 0; nt < 4; ++nt)
            Cst[(mh * 16 + quad * 4 + reg) * 256 + wave * 64 + nt * 16 + colq] =
                f2bf(acc[mt][nt][reg]);
      }
      __syncthreads();
#pragma unroll
      for (int c = 0; c < 4; ++c) {
        int chunk = c * 256 + tid;       // 0..1023 16B chunks (32 rows x 512B)
        int row = chunk >> 5;
        int col8 = (chunk & 31) * 8;
        int rr = row0 + half * 32 + row;
        if (rr < NN)
          *(uint4*)&ylbf[rr * IC + col8] = *(const uint4*)&Cst[row * 256 + col8];
      }
      __syncthreads();
    }
  } else {
    const int head = wave;
    float asv[4], adv[4];
#pragma unroll
    for (int j = 0; j < 4; ++j) {
      asv[j] = asrc[head * 64 + j * 16 + colq];
      adv[j] = adst[head * 64 + j * 16 + colq];
    }
#pragma unroll
    for (int half = 0; half < 2; ++half) {
#pragma unroll
      for (int mh = 0; mh < 2; ++mh) {
        const int mt = half * 2 + mh;
#pragma unroll
        for (int reg = 0; reg < 4; ++reg) {
          int rr = row0 + mt * 16 + quad * 4 + reg;
          float sA = 0.f, dA = 0.f;
#pragma unroll
          for (int j = 0; j < 4; ++j) {
            float hA = acc[mt][j][reg];
            sA = fmaf(hA, asv[j], sA);
            dA = fmaf(hA, adv[j], dA);
            Cst[(mh * 16 + quad * 4 + reg) * 256 + head * 64 + j * 16 + colq] =
                f2bf(hA);
          }
#pragma unroll
          for (int off = 1; off < 16; off <<= 1) {
            sA += __shfl_xor(sA, off, 64);
            dA += __shfl_xor(dA, off, 64);
          }
          if (rr < NN) {
            if (colq == 0) als[rr * 4 + head] = sA;
            else if (colq == 1) ald[rr * 4 + head] = dA;
          }
        }
      }
      __syncthreads();
#pragma unroll
      for (int c = 0; c < 4; ++c) {
        int chunk = c * 256 + tid;
        int row = chunk >> 5;
        int col8 = (chunk & 31) * 8;
        int rr = row0 + half * 32 + row;
        if (rr < NN)
          *(uint4*)&hbf[rr * IC + col8] = *(const uint4*)&Cst[row * 256 + col8];
      }
      __syncthreads();
    }
  }
}

// ---------------- CSR scan over 8 replicated histograms (1024 thr) ---------------
__global__ __launch_bounds__(1024) void k_scan(const int* __restrict__ counts8,
                                               int* __restrict__ coff,
                                               int* __restrict__ start) {
  __shared__ int red[16];
  __shared__ int buf[1024];
  const int tid = threadIdx.x, b = blockIdx.x;
  const int base = b * 1024;
  int pre = 0;
  for (int i = tid; i < base; i += 1024) {
    int s = 0;
#pragma unroll
    for (int k = 0; k < 8; ++k) s += counts8[k * P8 + i];
    pre += s;
  }
#pragma unroll
  for (int off = 1; off < 64; off <<= 1) pre += __shfl_xor(pre, off, 64);
  if ((tid & 63) == 0) red[tid >> 6] = pre;
  __syncthreads();
  int bpre = 0;
#pragma unroll
  for (int w = 0; w < 16; ++w) bpre += red[w];
  const int i = base + tid;  // < P8 always (49*1024 == P8)
  int pc[8];
  int tot = 0;
#pragma unroll
  for (int k = 0; k < 8; ++k) {
    pc[k] = counts8[k * P8 + i];
    tot += pc[k];
  }
  buf[tid] = tot;
  __syncthreads();
  for (int off = 1; off < 1024; off <<= 1) {
    int t = (tid >= off) ? buf[tid - off] : 0;
    __syncthreads();
    buf[tid] += t;
    __syncthreads();
  }
  int ex = bpre + buf[tid] - tot;  // exclusive global prefix for element i
  int run = ex;
#pragma unroll
  for (int k = 0; k < 8; ++k) {
    coff[k * P8 + i] = run;
    run += pc[k];
  }
  if (i < NN) start[i] = ex;
  if (b == 48 && tid == 1023) start[NN] = ex + tot;
}

// ---------------- atomic-free scatter: pos = coff[copy][dst] + rank ------------
__global__ __launch_bounds__(256) void k_scatter(const int* __restrict__ src,
                                                 const int* __restrict__ dst,
                                                 const int* __restrict__ coff,
                                                 const unsigned char* __restrict__ rank8,
                                                 int* __restrict__ srcs) {
  int e = blockIdx.x * 256 + threadIdx.x;
  int copy = blockIdx.x & 7;  // matches histogram block mapping
  int pos = coff[copy * P8 + dst[e]] + (int)rank8[e];
  srcs[pos] = src[e];
}

// ---------------- layer-1 aggregation (r7-proven gather: pattern ceiling) -------
// r9/r10 closed both concurrency and locality levers (unroll-8 and src-split
// both null/negative; ~3.7 TB/s effective random-gather). NEW: fused layer-2 BN
// partial stats (x1 values are already in registers — removes k_bnstats2 and
// its 25.6MB re-read). 8-way replicated S32 atomics, finalized in k_node2.
__global__ __launch_bounds__(256) void k_agg(const ushort4* __restrict__ hq,
                                             ushort4* __restrict__ x1,
                                             const float4* __restrict__ als4,
                                             const float4* __restrict__ ald4,
                                             const int* __restrict__ start,
                                             const int* __restrict__ srcs,
                                             const float4* __restrict__ lb4,
                                             const float4* __restrict__ cb4,
                                             float* __restrict__ S32) {
  __shared__ float lsp[2048];          // p-weights, then stats partials
  const int tid = threadIdx.x;
  const int wave = tid >> 6, lane = tid & 63, head = lane >> 4;
  const int n = blockIdx.x * 4 + wave;
  const float* als = (const float*)als4;
  const int s = start[n], t = start[n + 1];
  const int deg = t - s;
  const float4 aldv = ald4[n];
  int svk = -1;
  float p0 = 0.f, p1 = 0.f, p2 = 0.f, p3 = 0.f;
  if (lane < deg) {
    svk = srcs[s + lane];
    float4 a = als4[svk];
    p0 = __expf(lrelu(a.x + aldv.x));
    p1 = __expf(lrelu(a.y + aldv.y));
    p2 = __expf(lrelu(a.z + aldv.z));
    p3 = __expf(lrelu(a.w + aldv.w));
  }
  *(float4*)&lsp[wave * 256 + lane * 4] = make_float4(p0, p1, p2, p3);
  float d0 = p0, d1 = p1, d2 = p2, d3 = p3;
  const float aldh = head == 0 ? aldv.x : head == 1 ? aldv.y : head == 2 ? aldv.z : aldv.w;
  if (deg > 64) {
    for (int i = s + 64 + lane; i < t; i += 64) {
      float4 a = als4[srcs[i]];
      d0 += __expf(lrelu(a.x + aldv.x));
      d1 += __expf(lrelu(a.y + aldv.y));
      d2 += __expf(lrelu(a.z + aldv.z));
      d3 += __expf(lrelu(a.w + aldv.w));
    }
  }
#pragma unroll
  for (int off = 1; off < 64; off <<= 1) {
    d0 += __shfl_xor(d0, off, 64);
    d1 += __shfl_xor(d1, off, 64);
    d2 += __shfl_xor(d2, off, 64);
    d3 += __shfl_xor(d3, off, 64);
  }
  const float inv =
      1.f / ((head == 0 ? d0 : head == 1 ? d1 : head == 2 ? d2 : d3) + 1e-16f);
  float a0 = 0.f, a1 = 0.f, a2 = 0.f, a3 = 0.f;
  const int cnt = min(deg, 64);
  const int wbase = wave * 256 + head;
  int j = 0;
  for (; j + 4 <= cnt; j += 4) {
    int sv0 = __shfl(svk, j, 64), sv1 = __shfl(svk, j + 1, 64);
    int sv2 = __shfl(svk, j + 2, 64), sv3 = __shfl(svk, j + 3, 64);
    ushort4 hv0 = hq[sv0 * 64 + lane];
    ushort4 hv1 = hq[sv1 * 64 + lane];
    ushort4 hv2 = hq[sv2 * 64 + lane];
    ushort4 hv3 = hq[sv3 * 64 + lane];
    float w0 = lsp[wbase + j * 4], w1 = lsp[wbase + j * 4 + 4];
    float w2 = lsp[wbase + j * 4 + 8], w3 = lsp[wbase + j * 4 + 12];
    a0 = fmaf(w0, b2f(hv0.x), a0); a1 = fmaf(w0, b2f(hv0.y), a1);
    a2 = fmaf(w0, b2f(hv0.z), a2); a3 = fmaf(w0, b2f(hv0.w), a3);
    a0 = fmaf(w1, b2f(hv1.x), a0); a1 = fmaf(w1, b2f(hv1.y), a1);
    a2 = fmaf(w1, b2f(hv1.z), a2); a3 = fmaf(w1, b2f(hv1.w), a3);
    a0 = fmaf(w2, b2f(hv2.x), a0); a1 = fmaf(w2, b2f(hv2.y), a1);
    a2 = fmaf(w2, b2f(hv2.z), a2); a3 = fmaf(w2, b2f(hv2.w), a3);
    a0 = fmaf(w3, b2f(hv3.x), a0); a1 = fmaf(w3, b2f(hv3.y), a1);
    a2 = fmaf(w3, b2f(hv3.z), a2); a3 = fmaf(w3, b2f(hv3.w), a3);
  }
  for (; j < cnt; ++j) {
    int sv = __shfl(svk, j, 64);
    float w = lsp[wbase + j * 4];
    ushort4 hv = hq[sv * 64 + lane];
    a0 = fmaf(w, b2f(hv.x), a0);
    a1 = fmaf(w, b2f(hv.y), a1);
    a2 = fmaf(w, b2f(hv.z), a2);
    a3 = fmaf(w, b2f(hv.w), a3);
  }
  if (deg > 64) {
    for (int i = s + 64; i < t; ++i) {
      int sv = srcs[i];
      float av = als[sv * 4 + head];
      float p = __expf(lrelu(av + aldh));
      ushort4 hv = hq[sv * 64 + lane];
      a0 = fmaf(p, b2f(hv.x), a0);
      a1 = fmaf(p, b2f(hv.y), a1);
      a2 = fmaf(p, b2f(hv.z), a2);
      a3 = fmaf(p, b2f(hv.w), a3);
    }
  }
  ushort4 yb = x1[n * 64 + lane];
  float4 bb1 = lb4[lane], bb2 = cb4[lane];
  ushort4 rb;
  rb.x = f2bf(fmaxf(fmaf(a0, inv, b2f(yb.x) + bb1.x + bb2.x), 0.f));
  rb.y = f2bf(fmaxf(fmaf(a1, inv, b2f(yb.y) + bb1.y + bb2.y), 0.f));
  rb.z = f2bf(fmaxf(fmaf(a2, inv, b2f(yb.z) + bb1.z + bb2.z), 0.f));
  rb.w = f2bf(fmaxf(fmaf(a3, inv, b2f(yb.w) + bb1.w + bb2.w), 0.f));
  x1[n * 64 + lane] = rb;
  // ---- fused layer-2 BN partial stats (values already in registers) ----
  // each wave only ever touched its own lsp region, so overwrite is safe.
  {
    float f0 = b2f(rb.x), f1 = b2f(rb.y), f2 = b2f(rb.z), f3 = b2f(rb.w);
    *(float4*)&lsp[wave * 256 + lane * 4] = make_float4(f0, f1, f2, f3);
    *(float4*)&lsp[1024 + wave * 256 + lane * 4] =
        make_float4(f0 * f0, f1 * f1, f2 * f2, f3 * f3);
  }
  __syncthreads();
  float sa = lsp[tid] + lsp[256 + tid] + lsp[512 + tid] + lsp[768 + tid];
  float sb = lsp[1024 + tid] + lsp[1280 + tid] + lsp[1536 + tid] + lsp[1792 + tid];
  const int copy = blockIdx.x & 7;
  atomicAdd(&S32[copy * 512 + tid], sa);
  atomicAdd(&S32[copy * 512 + 256 + tid], sb);
}

// ---------------- layer 2 node kernel: stats finalize (8 copies) + projections --
__global__ __launch_bounds__(256) void k_node2(const ushort4* __restrict__ x1,
                                               const float* __restrict__ S32,
                                               const float* __restrict__ g3,
                                               const float* __restrict__ b3,
                                               const float4* __restrict__ Wl4,
                                               const float4* __restrict__ Wc4,
                                               const float* __restrict__ a3s,
                                               const float* __restrict__ a3d,
                                               const float* __restrict__ l3b,
                                               const float* __restrict__ c3b,
                                               float2* __restrict__ y32,
                                               float4* __restrict__ nd4) {
  __shared__ float sc[256], sh[256];
  const int tid = threadIdx.x;
  {
    float s1 = 0.f, s2 = 0.f;
#pragma unroll
    for (int c = 0; c < 8; ++c) {
      s1 += S32[c * 512 + tid];
      s2 += S32[c * 512 + 256 + tid];
    }
    float mu = s1 * (1.f / NN);
    float var = s2 * (1.f / NN) - mu * mu;
    float ss = g3[tid] / sqrtf(var + EPS);
    sc[tid] = ss;
    sh[tid] = b3[tid] - mu * ss;
  }
  __syncthreads();
  const int n = blockIdx.x * 4 + (tid >> 6);
  const int lane = tid & 63;
  ushort4 xb = x1[n * 64 + lane];
  float x0 = fmaf(b2f(xb.x), sc[lane * 4 + 0], sh[lane * 4 + 0]);
  float x1v = fmaf(b2f(xb.y), sc[lane * 4 + 1], sh[lane * 4 + 1]);
  float x2 = fmaf(b2f(xb.z), sc[lane * 4 + 2], sh[lane * 4 + 2]);
  float x3 = fmaf(b2f(xb.w), sc[lane * 4 + 3], sh[lane * 4 + 3]);
  float4 wa = Wl4[lane * 2], wb = Wl4[lane * 2 + 1];
  float y0 = x0 * wa.x + x1v * wa.z + x2 * wb.x + x3 * wb.z;
  float y1 = x0 * wa.y + x1v * wa.w + x2 * wb.y + x3 * wb.w;
  float4 ca = Wc4[lane * 2], cb = Wc4[lane * 2 + 1];
  float g0 = x0 * ca.x + x1v * ca.z + x2 * cb.x + x3 * cb.z;
  float g1 = x0 * ca.y + x1v * ca.w + x2 * cb.y + x3 * cb.w;
#pragma unroll
  for (int off = 1; off < 64; off <<= 1) {
    y0 += __shfl_xor(y0, off, 64);
    y1 += __shfl_xor(y1, off, 64);
    g0 += __shfl_xor(g0, off, 64);
    g1 += __shfl_xor(g1, off, 64);
  }
  if (lane == 0) {
    y32[n] = make_float2(y0 + l3b[0] + c3b[0], y1 + l3b[1] + c3b[1]);
    nd4[n] = make_float4(g0 * a3s[0] + g1 * a3s[1], g0, g1,
                         g0 * a3d[0] + g1 * a3d[1]);
  }
}

// ---------------- layer 2 softmax-aggregate + output, single pass ----------------
__global__ __launch_bounds__(256) void k_final(const int* __restrict__ start,
                                               const int* __restrict__ srcs,
                                               const float4* __restrict__ nd4,
                                               const float2* __restrict__ y32,
                                               float* __restrict__ out) {
  const int tid = threadIdx.x;
  const int n = blockIdx.x * 16 + (tid >> 4);
  const int li = tid & 15;
  const int s = start[n], t = start[n + 1];
  const float ad = nd4[n].w;
  float den = 0.f, a0 = 0.f, a1 = 0.f;
  for (int ii = s + li; ii < t; ii += 16) {
    float4 vv = nd4[srcs[ii]];
    float p = __expf(lrelu(vv.x + ad));
    den += p;
    a0 = fmaf(p, vv.y, a0);
    a1 = fmaf(p, vv.z, a1);
  }
#pragma unroll
  for (int off = 1; off < 16; off <<= 1) {
    den += __shfl_xor(den, off, 64);
    a0 += __shfl_xor(a0, off, 64);
    a1 += __shfl_xor(a1, off, 64);
  }
  if (li == 0) {
    float2 y = y32[n];
    float inv = 1.f / (den + 1e-16f);
    out[2 * n] = fmaxf(fmaf(a0, inv, y.x), 0.f);
    out[2 * n + 1] = fmaxf(fmaf(a1, inv, y.y), 0.f);
  }
}

extern "C" void kernel_launch(void* const* d_in, const int* in_sizes, int n_in,
                              void* d_out, int out_size, void* d_ws, size_t ws_size,
                              hipStream_t stream) {
  const float* x = (const float*)d_in[0];
  const int* ei = (const int*)d_in[1];
  const float* bn1_g = (const float*)d_in[2];
  const float* bn1_b = (const float*)d_in[3];
  const float* lin1_W = (const float*)d_in[4];
  const float* lin1_b = (const float*)d_in[5];
  const float* con1_W = (const float*)d_in[6];
  const float* con1_as = (const float*)d_in[7];
  const float* con1_ad = (const float*)d_in[8];
  const float* con1_b = (const float*)d_in[9];
  const float* bn3_g = (const float*)d_in[10];
  const float* bn3_b = (const float*)d_in[11];
  const float* lin3_W = (const float*)d_in[12];
  const float* lin3_b = (const float*)d_in[13];
  const float* con3_W = (const float*)d_in[14];
  const float* con3_as = (const float*)d_in[15];
  const float* con3_ad = (const float*)d_in[16];
  const float* con3_b = (const float*)d_in[17];
  float* ws = (float*)d_ws;
  const int* srcA = ei;
  const int* dstA = ei + NE;

  float* S1 = ws + OFF_S1;
  float* S2 = ws + OFF_S2;
  float* S32 = ws + OFF_S32;
  int* counts8 = (int*)(ws + OFF_C8);
  int* coff = (int*)(ws + OFF_COFF);
  int* start = (int*)(ws + OFF_START);
  unsigned char* rank8 = (unsigned char*)(ws + OFF_RANK);
  float* als = ws + OFF_ALS;
  float* ald = ws + OFF_ALD;
  int* srcs = (int*)(ws + OFF_SRCS);
  float2* y32 = (float2*)(ws + OFF_Y32);
  float4* nd4 = (float4*)(ws + OFF_ND4);
  unsigned short* Bfh = (unsigned short*)(ws + OFF_BFH);
  unsigned short* hbf = (unsigned short*)(ws + OFF_HBF);
  unsigned short* ylbf = (unsigned short*)(ws + OFF_YLBF);  // becomes x1 in place

  hipMemsetAsync(ws, 0, (size_t)ZERO_END * sizeof(float), stream);

  k_prep<<<1536, 256, 0, stream>>>(x, S1, S2, lin1_W, con1_W, Bfh);
  k_gemm<<<1568 + 3125, 256, 0, stream>>>(x, S1, S2, bn1_g, bn1_b, Bfh, ylbf,
                                          hbf, con1_as, con1_ad, als, ald, dstA,
                                          counts8, rank8);
  k_scan<<<49, 1024, 0, stream>>>(counts8, coff, start);
  k_scatter<<<3125, 256, 0, stream>>>(srcA, dstA, coff, rank8, srcs);
  k_agg<<<12500, 256, 0, stream>>>((const ushort4*)hbf, (ushort4*)ylbf,
                                   (const float4*)als, (const float4*)ald, start,
                                   srcs, (const float4*)lin1_b,
                                   (const float4*)con1_b, S32);
  k_node2<<<12500, 256, 0, stream>>>((const ushort4*)ylbf, S32, bn3_g, bn3_b,
                                     (const float4*)lin3_W, (const float4*)con3_W,
                                     con3_as, con3_ad, lin3_b, con3_b, y32, nd4);
  k_final<<<3125, 256, 0, stream>>>(start, srcs, nd4, y32, (float*)d_out);
}